// Round 9
// baseline (108.130 us; speedup 1.0000x reference)
//
#include <hip/hip_runtime.h>
#include <hip/hip_bf16.h>

// B=4, C=512, IC=128, N=3136
// prep_w     : bf16-ize weights  Wb[256][512] (theta|glob stacked), wupb[512][128]
// conv_in_f  : fused MFMA GEMM from maps (f32) with in-LDS bf16 transpose staging.
//              Writes Tt bf16 [b][n][ic] (theta pre-norm, transposed) and
//              Gpre bf16 [b][ic][n] (glob pre-norm) + per-block channel partials.
// stats_fin  : reduce partials -> st[512] (means, rstds)
// attn_k     : KV-split (S=7, 14 tiles each; KVBLK=32) flash attention,
//              32x32x16 MFMA, BN folded:
//                K = raw Tt (softmax row-constant drops),
//                Q = (t-mu)*rho^2*log2e/N at load (exp2 scale folded),
//                V = raw Gpre (BN applied post-hoc in conv_out_f).
//              Swapped QK^T (mfma(K,Q)); P in-register via v_perm pack +
//              v_permlane32_swap. K/V LDS-staged (global_load_lds, XOR-swizzle,
//              dbuf, 32KB total -> 4 blocks/CU).
//              Partials: Opart[s][b][n][ic] BF16 + dpart f32 (overlays psum).
// conv_out_f : fused combine (7 bf16 partials) + de-norm + MFMA GEMM + bias
//              + residual -> out.

typedef __attribute__((ext_vector_type(8))) short bf16x8;
typedef __attribute__((ext_vector_type(4))) float f32x4;
typedef __attribute__((ext_vector_type(16))) float f32x16;
typedef __attribute__((ext_vector_type(4))) short s16x4;

#define NTOK 3136
#define NELEM 1605632   // 4*128*3136
#define NSPLIT 7

__device__ inline float bf2f(short u) {
    union { unsigned int i; float f; } v;
    v.i = ((unsigned int)(unsigned short)u) << 16;
    return v.f;
}
__device__ inline short f2bf(float x) {
    union { float f; unsigned int i; } v;
    v.f = x;
    unsigned int r = v.i + 0x7FFFu + ((v.i >> 16) & 1u); // RNE
    return (short)(r >> 16);
}
// pack two f32 -> u32 of 2 bf16 (truncation) in ONE v_perm_b32
__device__ inline unsigned pk2(float lo, float hi) {
    union { float f; unsigned u; } a, b;
    a.f = lo; b.f = hi;
    return __builtin_amdgcn_perm(b.u, a.u, 0x07060302u);
}
// v_permlane32_swap_b32: a.hi-lanes <-> b.lo-lanes
__device__ inline void pl32swap(unsigned &a, unsigned &b) {
    asm("v_permlane32_swap_b32 %0, %1" : "+v"(a), "+v"(b));
}
__device__ inline void glds16(const void* g, void* l) {
    __builtin_amdgcn_global_load_lds((const __attribute__((address_space(1))) void*)g,
                                     (__attribute__((address_space(3))) void*)l, 16, 0, 0);
}

// ---------------- prep: weights -> bf16 ---------------------------------
__global__ __launch_bounds__(256) void prep_w(const float* __restrict__ wt,
                                              const float* __restrict__ wg,
                                              const float* __restrict__ wup,
                                              short* __restrict__ Wb,
                                              short* __restrict__ wupb)
{
    const int i = blockIdx.x * 256 + threadIdx.x;
    if (i < 131072) {
        const int r = i >> 9;
        const int c = i & 511;
        const float w = (r < 128) ? wt[(size_t)r * 512 + c] : wg[(size_t)(r - 128) * 512 + c];
        Wb[i] = f2bf(w);
    } else {
        const int j = i - 131072;
        wupb[j] = f2bf(wup[j]);
    }
}

// ---------------- fused input conv --------------------------------------
// grid (98, 4) = (32-n tile, b), block 256 = 4 waves.
__global__ __launch_bounds__(256) void conv_in_f(const float* __restrict__ maps,
                                                 const short* __restrict__ Wb,
                                                 short* __restrict__ Tt,
                                                 short* __restrict__ Gpre,
                                                 float* __restrict__ psum,
                                                 float* __restrict__ psq)
{
    const int nt = blockIdx.x, b = blockIdx.y;
    const int n0 = nt * 32;
    const int t = threadIdx.x;
    const int w = __builtin_amdgcn_readfirstlane(t >> 6);
    const int lane = t & 63;
    const int l15 = lane & 15, lhi = lane >> 4;

    __shared__ short Bt[32][136];   // [n][c-chunk], +8 pad

    const float* mp = maps + (size_t)b * 512 * NTOK + n0;
    const int cl = t >> 3;          // 0..31
    const int f4 = t & 7;           // float4 index along n

    f32x4 acc[4][2];
#pragma unroll
    for (int g = 0; g < 4; g++)
#pragma unroll
        for (int j = 0; j < 2; j++) acc[g][j] = f32x4{0.f, 0.f, 0.f, 0.f};

    f32x4 rg[4];
#pragma unroll
    for (int p = 0; p < 4; p++)
        rg[p] = *(const f32x4*)(mp + (size_t)(p * 32 + cl) * NTOK + f4 * 4);

    for (int kc = 0; kc < 4; kc++) {
        __syncthreads();
#pragma unroll
        for (int p = 0; p < 4; p++) {
            const int cc = p * 32 + cl;
#pragma unroll
            for (int i = 0; i < 4; i++) Bt[f4 * 4 + i][cc] = f2bf(rg[p][i]);
        }
        if (kc < 3) {
#pragma unroll
            for (int p = 0; p < 4; p++)
                rg[p] = *(const f32x4*)(mp + (size_t)((kc + 1) * 128 + p * 32 + cl) * NTOK + f4 * 4);
        }
        __syncthreads();
#pragma unroll
        for (int ks = 0; ks < 4; ks++) {
            bf16x8 af[4], bv[2];
#pragma unroll
            for (int g = 0; g < 4; g++)
                af[g] = *(const bf16x8*)(Wb + (size_t)(w * 64 + g * 16 + l15) * 512 + kc * 128 + ks * 32 + lhi * 8);
#pragma unroll
            for (int j = 0; j < 2; j++)
                bv[j] = *(const bf16x8*)(&Bt[j * 16 + l15][ks * 32 + lhi * 8]);
#pragma unroll
            for (int g = 0; g < 4; g++)
#pragma unroll
                for (int j = 0; j < 2; j++)
                    acc[g][j] = __builtin_amdgcn_mfma_f32_16x16x32_bf16(af[g], bv[j], acc[g][j], 0, 0, 0);
        }
    }

    // ---- outputs. D layout: col(l15)=n_local, row(lhi*4+r)=ch_local ----
    if (w < 2) {
#pragma unroll
        for (int g = 0; g < 4; g++)
#pragma unroll
            for (int j = 0; j < 2; j++) {
                s16x4 v;
#pragma unroll
                for (int r = 0; r < 4; r++) v[r] = f2bf(acc[g][j][r]);
                *(s16x4*)(Tt + ((size_t)b * NTOK + n0 + j * 16 + l15) * 128 + w * 64 + g * 16 + lhi * 4) = v;
            }
    } else {
#pragma unroll
        for (int g = 0; g < 4; g++)
#pragma unroll
            for (int j = 0; j < 2; j++)
#pragma unroll
                for (int r = 0; r < 4; r++) {
                    const int icg = (w - 2) * 64 + g * 16 + lhi * 4 + r;
                    Gpre[((size_t)b * 128 + icg) * NTOK + n0 + j * 16 + l15] = f2bf(acc[g][j][r]);
                }
    }
#pragma unroll
    for (int g = 0; g < 4; g++)
#pragma unroll
        for (int r = 0; r < 4; r++) {
            float s = acc[g][0][r] + acc[g][1][r];
            float q = acc[g][0][r] * acc[g][0][r] + acc[g][1][r] * acc[g][1][r];
#pragma unroll
            for (int off = 1; off < 16; off <<= 1) {
                s += __shfl_xor(s, off);
                q += __shfl_xor(q, off);
            }
            if (l15 == 0) {
                const int ch = w * 64 + g * 16 + lhi * 4 + r;  // 0-127 theta, 128-255 glob
                psum[(size_t)ch * 392 + b * 98 + nt] = s;
                psq [(size_t)ch * 392 + b * 98 + nt] = q;
            }
        }
}

// ---------------- finalize stats ----------------------------------------
__global__ __launch_bounds__(64) void stats_fin(const float* __restrict__ psum,
                                                const float* __restrict__ psq,
                                                float* __restrict__ st)
{
    const int ch = blockIdx.x;
    const int lane = threadIdx.x;
    float s = 0.f, q = 0.f;
    for (int i = lane; i < 392; i += 64) {
        s += psum[(size_t)ch * 392 + i];
        q += psq [(size_t)ch * 392 + i];
    }
#pragma unroll
    for (int off = 32; off; off >>= 1) { s += __shfl_xor(s, off); q += __shfl_xor(q, off); }
    if (lane == 0) {
        const float mean = s / 12544.f;
        const float var = q / 12544.f - mean * mean;
        st[ch] = mean;
        st[256 + ch] = rsqrtf(var + 1e-5f);
    }
}

// ---------------- attention: 32x32 MFMA, in-register P, KVBLK=32 --------
// grid (25, B=4, S=7), block 256 = 4 waves; wave owns 32 q-rows.
// 98 m-tiles of 32; split s handles tiles s, s+7, ... (14 each, exact).
__global__ __launch_bounds__(256, 4) void attn_k(const short* __restrict__ Tt,
                                                 const short* __restrict__ Gpre,
                                                 const float* __restrict__ st,
                                                 short* __restrict__ Opart,
                                                 float* __restrict__ dpart)
{
    constexpr int N = NTOK;
    const int b = blockIdx.y, s = blockIdx.z;
    const int w = __builtin_amdgcn_readfirstlane(threadIdx.x >> 6);
    const int lane = threadIdx.x & 63;
    const int l31 = lane & 31, hi = lane >> 5;
    const int q0w = blockIdx.x * 128 + w * 32;

    __shared__ __align__(16) short Kl[2][32][128];  // 16 KB: K tile [m][ic]
    __shared__ __align__(16) short Vl[2][128][32];  // 16 KB: V tile [ic][m]

    const short* tb = Tt + (size_t)b * N * 128;
    const short* gb = Gpre + (size_t)b * 128 * N;

    // Q B-frags (col=q=l31, k(ic)=ks*16+hi*8+j), fold: q=(t-mu)*rho^2*log2e/N
    const float kexp = 1.44269504089f / (float)N;
    bf16x8 qf[8];
    {
        int row = q0w + l31; row = row < N ? row : N - 1;
        const short* qp = tb + (size_t)row * 128;
#pragma unroll
        for (int ks = 0; ks < 8; ks++) {
            const int c0 = ks * 16 + hi * 8;
            const bf16x8 v = *(const bf16x8*)(qp + c0);
            const f32x4 mA = *(const f32x4*)(st + c0);
            const f32x4 mB = *(const f32x4*)(st + c0 + 4);
            const f32x4 rA = *(const f32x4*)(st + 256 + c0);
            const f32x4 rB = *(const f32x4*)(st + 256 + c0 + 4);
            bf16x8 q;
#pragma unroll
            for (int j = 0; j < 4; j++) q[j] = f2bf((bf2f(v[j]) - mA[j]) * (rA[j] * rA[j] * kexp));
#pragma unroll
            for (int j = 0; j < 4; j++) q[4 + j] = f2bf((bf2f(v[4 + j]) - mB[j]) * (rB[j] * rB[j] * kexp));
            qf[ks] = q;
        }
    }

    f32x16 accv[4];
#pragma unroll
    for (int it = 0; it < 4; it++)
#pragma unroll
        for (int r = 0; r < 16; r++) accv[it][r] = 0.f;
    float denom = 0.f;

    auto STAGE = [&](int bufi, int m0) {
        // K: 32 rows x 256B; wave w stages rows [w*8, w*8+8): 2 instrs x 4 rows.
#pragma unroll
        for (int i = 0; i < 2; i++) {
            const int rb = w * 8 + i * 4;
            const int krow = rb + (lane >> 4);
            const int ls = (lane & 15) ^ (krow & 7);      // pre-swizzled source unit
            glds16(tb + (size_t)(m0 + krow) * 128 + ls * 8, (void*)&Kl[bufi][rb][0]);
        }
        // V: 128 rows x 64B; wave w stages rows [w*32, w*32+32): 2 instrs x 16 rows.
#pragma unroll
        for (int i = 0; i < 2; i++) {
            const int rb = w * 32 + i * 16;
            const int vrow = rb + (lane >> 2);
            const int ls = (lane & 3) ^ ((vrow >> 1) & 3);
            glds16(gb + (size_t)vrow * N + m0 + ls * 8, (void*)&Vl[bufi][rb][0]);
        }
    };

    int mt = s;
    STAGE(0, mt * 32);
    __syncthreads();
    int buf = 0;

    const int frk = (l31 & 7) << 4;           // K read swizzle (row = l31)
    const int frv = ((l31 >> 1) & 3) << 4;    // V read swizzle (row = it*32+l31)

    // exp2 + pack the 32-m tile -> two PV A-frags (k-steps m 0-15, 16-31)
    auto mkpa = [&](const f32x16 &sv, bf16x8 *dst) {
        float e[16];
#pragma unroll
        for (int r = 0; r < 16; r++) { e[r] = exp2f(sv[r]); denom += e[r]; }
        unsigned c0 = pk2(e[0], e[1]),  c1 = pk2(e[2], e[3]);
        unsigned c2 = pk2(e[4], e[5]),  c3 = pk2(e[6], e[7]);
        unsigned c4 = pk2(e[8], e[9]),  c5 = pk2(e[10], e[11]);
        unsigned c6 = pk2(e[12], e[13]), c7 = pk2(e[14], e[15]);
        pl32swap(c0, c2); pl32swap(c1, c3); pl32swap(c4, c6); pl32swap(c5, c7);
        union U { unsigned u[4]; bf16x8 v; } f0, f1;
        f0.u[0] = c0; f0.u[1] = c1; f0.u[2] = c2; f0.u[3] = c3;
        f1.u[0] = c4; f1.u[1] = c5; f1.u[2] = c6; f1.u[3] = c7;
        dst[0] = f0.v; dst[1] = f1.v;
    };

    for (int t = 0; t < 14; ++t) {
        if (t + 1 < 14) STAGE(buf ^ 1, (mt + NSPLIT) * 32);

        // --- QK^T: A = K rows (m 0..31), B = Q; 8 k-steps over 128 ic ---
        f32x16 sv0;
#pragma unroll
        for (int r = 0; r < 16; r++) sv0[r] = 0.f;
#pragma unroll
        for (int ks = 0; ks < 8; ks++) {
            const int co = (ks * 32 + hi * 16) ^ frk;
            bf16x8 kf0 = *(const bf16x8*)((const char*)&Kl[buf][l31][0] + co);
            sv0 = __builtin_amdgcn_mfma_f32_32x32x16_bf16(kf0, qf[ks], sv0, 0, 0, 0);
        }

        // --- exp2 -> in-register P A-frags (no LDS) ---
        bf16x8 pa[2];
        mkpa(sv0, pa);

        // --- PV: A = P (rows q), B = V (cols ic), k = m (2 k-steps) ---
#pragma unroll
        for (int kp = 0; kp < 2; kp++) {
            const int cv = kp * 32 + hi * 16;
#pragma unroll
            for (int it = 0; it < 4; it++) {
                bf16x8 vf = *(const bf16x8*)((const char*)&Vl[buf][it * 32 + l31][0] + (cv ^ frv));
                accv[it] = __builtin_amdgcn_mfma_f32_32x32x16_bf16(pa[kp], vf, accv[it], 0, 0, 0);
            }
        }
        __syncthreads();
        buf ^= 1;
        mt += NSPLIT;
    }

    // denom: lane holds sum over its m-half for q=l31; combine halves
    denom += __shfl_xor(denom, 32);

    short* op = Opart + ((size_t)(s * 4 + b)) * N * 128;
    // accv layout: col(l31)=ic_local, row=(r&3)+8(r>>2)+4hi = q_local
#pragma unroll
    for (int it = 0; it < 4; it++)
#pragma unroll
        for (int r = 0; r < 16; r++) {
            const int n = q0w + (r & 3) + 8 * (r >> 2) + 4 * hi;
            if (n < N) op[(size_t)n * 128 + it * 32 + l31] = f2bf(accv[it][r]);
        }
    if (lane < 32) {
        const int n = q0w + l31;
        if (n < N) dpart[(size_t)(s * 4 + b) * N + n] = denom;
    }
}

// ---------------- fused combine + de-norm + up conv + residual ----------
// grid (98, 4), block 256 = 4 waves.
__global__ __launch_bounds__(256) void conv_out_f(const short* __restrict__ Opart,
                                                  const float* __restrict__ dpart,
                                                  const float* __restrict__ st,
                                                  const short* __restrict__ wupb,
                                                  const float* __restrict__ bup,
                                                  const float* __restrict__ maps,
                                                  float* __restrict__ out)
{
    const int n0 = blockIdx.x * 32, b = blockIdx.y;
    const int t = threadIdx.x;

    __shared__ float denl[32];
    __shared__ __align__(16) short Yl[32][128];    // XOR-swizzled rows

    if (t < 32) {
        float d = 0.f;
#pragma unroll
        for (int s = 0; s < NSPLIT; s++) d += dpart[(size_t)(s * 4 + b) * NTOK + n0 + t];
        denl[t] = 1.0f / d;
    }
    __syncthreads();

#pragma unroll
    for (int g = 0; g < 2; g++) {
        const int e = t + g * 256;          // 0..511
        const int nl = e >> 4, icg = (e & 15) * 8;
        const float rdn = denl[nl];
        float sum[8] = {0.f, 0.f, 0.f, 0.f, 0.f, 0.f, 0.f, 0.f};
#pragma unroll
        for (int s = 0; s < NSPLIT; s++) {
            const size_t base = ((size_t)(s * 4 + b) * NTOK + n0 + nl) * 128 + icg;
            const bf16x8 a = *(const bf16x8*)(Opart + base);
#pragma unroll
            for (int j = 0; j < 8; j++) sum[j] += bf2f(a[j]);
        }
        const f32x4 mA = *(const f32x4*)(st + 128 + icg);
        const f32x4 mB = *(const f32x4*)(st + 128 + icg + 4);
        const f32x4 rA = *(const f32x4*)(st + 384 + icg);
        const f32x4 rB = *(const f32x4*)(st + 384 + icg + 4);
        s16x4 v0, v1;
#pragma unroll
        for (int j = 0; j < 4; j++) v0[j] = f2bf((sum[j] * rdn - mA[j]) * rA[j]);
#pragma unroll
        for (int j = 0; j < 4; j++) v1[j] = f2bf((sum[4 + j] * rdn - mB[j]) * rB[j]);
        char* ybase = (char*)&Yl[nl][0];
        const int sw = (nl & 7) << 4;
        *(s16x4*)(ybase + ((icg * 2) ^ sw)) = v0;
        *(s16x4*)(ybase + (((icg * 2) ^ sw) + 8)) = v1;
    }
    __syncthreads();

    const int wv = __builtin_amdgcn_readfirstlane(t >> 6);
    const int lane = t & 63;
    const int l15 = lane & 15, lhi = lane >> 4;
    const int c0 = wv * 128;
    const int fY = (l15 & 7) << 4;

    f32x4 acc[8][2];
#pragma unroll
    for (int g = 0; g < 8; g++)
#pragma unroll
        for (int j = 0; j < 2; j++) acc[g][j] = f32x4{0.f, 0.f, 0.f, 0.f};

#pragma unroll
    for (int ks = 0; ks < 4; ks++) {
        bf16x8 af[8], bv[2];
#pragma unroll
        for (int g = 0; g < 8; g++)
            af[g] = *(const bf16x8*)(wupb + (size_t)(c0 + g * 16 + l15) * 128 + ks * 32 + lhi * 8);
#pragma unroll
        for (int j = 0; j < 2; j++)
            bv[j] = *(const bf16x8*)((const char*)&Yl[j * 16 + l15][0] + ((ks * 64 + lhi * 16) ^ fY));
#pragma unroll
        for (int g = 0; g < 8; g++)
#pragma unroll
            for (int j = 0; j < 2; j++)
                acc[g][j] = __builtin_amdgcn_mfma_f32_16x16x32_bf16(af[g], bv[j], acc[g][j], 0, 0, 0);
    }
#pragma unroll
    for (int g = 0; g < 8; g++)
#pragma unroll
        for (int j = 0; j < 2; j++)
#pragma unroll
            for (int r = 0; r < 4; r++) {
                const int c = c0 + g * 16 + lhi * 4 + r;
                const int n = n0 + j * 16 + l15;
                const size_t o = ((size_t)b * 512 + c) * NTOK + n;
                out[o] = acc[g][j][r] + bup[c] + maps[o];
            }
}

extern "C" void kernel_launch(void* const* d_in, const int* in_sizes, int n_in,
                              void* d_out, int out_size, void* d_ws, size_t ws_size,
                              hipStream_t stream)
{
    const float* maps    = (const float*)d_in[0];
    const float* w_theta = (const float*)d_in[1];
    const float* w_glob  = (const float*)d_in[5];
    const float* w_up    = (const float*)d_in[7];
    const float* b_up    = (const float*)d_in[8];
    float* out = (float*)d_out;

    // workspace (~30.1 MB); dpart overlays psum (dead after stats_fin,
    // fully rewritten by conv_in_f each launch -> replay-safe)
    short* Tt    = (short*)d_ws;               // NELEM (theta pre-norm, [b][n][ic])
    short* Gpre  = Tt + NELEM;                 // NELEM (glob pre-norm, [b][ic][n])
    short* Wb    = Gpre + NELEM;               // 131072 shorts
    short* wupb  = Wb + 131072;                // 65536 shorts
    float* st    = (float*)(wupb + 65536);     // 512 f32
    float* psum  = st + 512;                   // 256*392 f32
    float* psq   = psum + 100352;              // 256*392 f32
    float* dpart = psum;                       // overlay: NSPLIT*4*3136 f32 <= psum
    short* Opart = (short*)(psq + 100352);     // NSPLIT*4*3136*128 bf16 = 22.5 MB

    prep_w    <<<768,             256, 0, stream>>>(w_theta, w_glob, w_up, Wb, wupb);
    conv_in_f <<<dim3(98, 4),     256, 0, stream>>>(maps, Wb, Tt, Gpre, psum, psq);
    stats_fin <<<256,             64,  0, stream>>>(psum, psq, st);
    attn_k    <<<dim3(25, 4, NSPLIT), 256, 0, stream>>>(Tt, Gpre, st, Opart, dpart);
    conv_out_f<<<dim3(98, 4),     256, 0, stream>>>(Opart, dpart, st, wupb, b_up, maps, out);
}

// Round 10
// 89.307 us; speedup vs baseline: 1.2108x; 1.2108x over previous
//
#include <hip/hip_runtime.h>
#include <hip/hip_bf16.h>

// B=4, C=512, IC=128, N=3136
// prep_w     : bf16-ize weights  Wb[256][512] (theta|glob stacked), wupb[512][128]
// conv_in_f  : fused MFMA GEMM from maps (f32) with in-LDS bf16 transpose staging.
//              Writes Tt bf16 [b][n][ic] (theta pre-norm, transposed) and
//              Gpre bf16 [b][ic][n] (glob pre-norm) + per-block channel partials.
// stats_fin  : reduce partials -> st[512] (means, rstds)
// attn_k     : KV-split (S=4) flash attention, 32x32x16 MFMA, KVBLK=64, BN folded:
//                K = raw Tt (softmax row-constant drops),
//                Q = (t-mu)*rho^2*log2e/N at load (exp2 scale folded),
//                V = raw Gpre (BN applied post-hoc in conv_out_f).
//              Swapped QK^T (mfma(K,Q)), dual independent accum chains;
//              P in-register via v_perm pack + v_permlane32_swap.
//              K/V LDS-staged (global_load_lds, XOR-swizzle, dbuf). NO setprio
//              (R8 post-mortem: hurts barrier-locked waves, cf. m190).
//              Partials: Opart[s][b][n][ic] BF16 + dpart f32.
// conv_out_f : fused combine (bf16 partials) + de-norm + MFMA GEMM + bias
//              + residual -> out.

typedef __attribute__((ext_vector_type(8))) short bf16x8;
typedef __attribute__((ext_vector_type(4))) float f32x4;
typedef __attribute__((ext_vector_type(16))) float f32x16;
typedef __attribute__((ext_vector_type(4))) short s16x4;

#define NTOK 3136
#define NELEM 1605632   // 4*128*3136
#define NSPLIT 4

__device__ inline float bf2f(short u) {
    union { unsigned int i; float f; } v;
    v.i = ((unsigned int)(unsigned short)u) << 16;
    return v.f;
}
__device__ inline short f2bf(float x) {
    union { float f; unsigned int i; } v;
    v.f = x;
    unsigned int r = v.i + 0x7FFFu + ((v.i >> 16) & 1u); // RNE
    return (short)(r >> 16);
}
// pack two f32 -> u32 of 2 bf16 (truncation) in ONE v_perm_b32
__device__ inline unsigned pk2(float lo, float hi) {
    union { float f; unsigned u; } a, b;
    a.f = lo; b.f = hi;
    return __builtin_amdgcn_perm(b.u, a.u, 0x07060302u);
}
// v_permlane32_swap_b32: a.hi-lanes <-> b.lo-lanes
__device__ inline void pl32swap(unsigned &a, unsigned &b) {
    asm("v_permlane32_swap_b32 %0, %1" : "+v"(a), "+v"(b));
}
__device__ inline void glds16(const void* g, void* l) {
    __builtin_amdgcn_global_load_lds((const __attribute__((address_space(1))) void*)g,
                                     (__attribute__((address_space(3))) void*)l, 16, 0, 0);
}

// ---------------- prep: weights -> bf16 ---------------------------------
__global__ __launch_bounds__(256) void prep_w(const float* __restrict__ wt,
                                              const float* __restrict__ wg,
                                              const float* __restrict__ wup,
                                              short* __restrict__ Wb,
                                              short* __restrict__ wupb)
{
    const int i = blockIdx.x * 256 + threadIdx.x;
    if (i < 131072) {
        const int r = i >> 9;
        const int c = i & 511;
        const float w = (r < 128) ? wt[(size_t)r * 512 + c] : wg[(size_t)(r - 128) * 512 + c];
        Wb[i] = f2bf(w);
    } else {
        const int j = i - 131072;
        wupb[j] = f2bf(wup[j]);
    }
}

// ---------------- fused input conv --------------------------------------
// grid (98, 4) = (32-n tile, b), block 256 = 4 waves.
__global__ __launch_bounds__(256) void conv_in_f(const float* __restrict__ maps,
                                                 const short* __restrict__ Wb,
                                                 short* __restrict__ Tt,
                                                 short* __restrict__ Gpre,
                                                 float* __restrict__ psum,
                                                 float* __restrict__ psq)
{
    const int nt = blockIdx.x, b = blockIdx.y;
    const int n0 = nt * 32;
    const int t = threadIdx.x;
    const int w = __builtin_amdgcn_readfirstlane(t >> 6);
    const int lane = t & 63;
    const int l15 = lane & 15, lhi = lane >> 4;

    __shared__ short Bt[32][136];   // [n][c-chunk], +8 pad

    const float* mp = maps + (size_t)b * 512 * NTOK + n0;
    const int cl = t >> 3;          // 0..31
    const int f4 = t & 7;           // float4 index along n

    f32x4 acc[4][2];
#pragma unroll
    for (int g = 0; g < 4; g++)
#pragma unroll
        for (int j = 0; j < 2; j++) acc[g][j] = f32x4{0.f, 0.f, 0.f, 0.f};

    f32x4 rg[4];
#pragma unroll
    for (int p = 0; p < 4; p++)
        rg[p] = *(const f32x4*)(mp + (size_t)(p * 32 + cl) * NTOK + f4 * 4);

    for (int kc = 0; kc < 4; kc++) {
        __syncthreads();
#pragma unroll
        for (int p = 0; p < 4; p++) {
            const int cc = p * 32 + cl;
#pragma unroll
            for (int i = 0; i < 4; i++) Bt[f4 * 4 + i][cc] = f2bf(rg[p][i]);
        }
        if (kc < 3) {
#pragma unroll
            for (int p = 0; p < 4; p++)
                rg[p] = *(const f32x4*)(mp + (size_t)((kc + 1) * 128 + p * 32 + cl) * NTOK + f4 * 4);
        }
        __syncthreads();
#pragma unroll
        for (int ks = 0; ks < 4; ks++) {
            bf16x8 af[4], bv[2];
#pragma unroll
            for (int g = 0; g < 4; g++)
                af[g] = *(const bf16x8*)(Wb + (size_t)(w * 64 + g * 16 + l15) * 512 + kc * 128 + ks * 32 + lhi * 8);
#pragma unroll
            for (int j = 0; j < 2; j++)
                bv[j] = *(const bf16x8*)(&Bt[j * 16 + l15][ks * 32 + lhi * 8]);
#pragma unroll
            for (int g = 0; g < 4; g++)
#pragma unroll
                for (int j = 0; j < 2; j++)
                    acc[g][j] = __builtin_amdgcn_mfma_f32_16x16x32_bf16(af[g], bv[j], acc[g][j], 0, 0, 0);
        }
    }

    // ---- outputs. D layout: col(l15)=n_local, row(lhi*4+r)=ch_local ----
    if (w < 2) {
#pragma unroll
        for (int g = 0; g < 4; g++)
#pragma unroll
            for (int j = 0; j < 2; j++) {
                s16x4 v;
#pragma unroll
                for (int r = 0; r < 4; r++) v[r] = f2bf(acc[g][j][r]);
                *(s16x4*)(Tt + ((size_t)b * NTOK + n0 + j * 16 + l15) * 128 + w * 64 + g * 16 + lhi * 4) = v;
            }
    } else {
#pragma unroll
        for (int g = 0; g < 4; g++)
#pragma unroll
            for (int j = 0; j < 2; j++)
#pragma unroll
                for (int r = 0; r < 4; r++) {
                    const int icg = (w - 2) * 64 + g * 16 + lhi * 4 + r;
                    Gpre[((size_t)b * 128 + icg) * NTOK + n0 + j * 16 + l15] = f2bf(acc[g][j][r]);
                }
    }
#pragma unroll
    for (int g = 0; g < 4; g++)
#pragma unroll
        for (int r = 0; r < 4; r++) {
            float s = acc[g][0][r] + acc[g][1][r];
            float q = acc[g][0][r] * acc[g][0][r] + acc[g][1][r] * acc[g][1][r];
#pragma unroll
            for (int off = 1; off < 16; off <<= 1) {
                s += __shfl_xor(s, off);
                q += __shfl_xor(q, off);
            }
            if (l15 == 0) {
                const int ch = w * 64 + g * 16 + lhi * 4 + r;  // 0-127 theta, 128-255 glob
                psum[(size_t)ch * 392 + b * 98 + nt] = s;
                psq [(size_t)ch * 392 + b * 98 + nt] = q;
            }
        }
}

// ---------------- finalize stats ----------------------------------------
__global__ __launch_bounds__(64) void stats_fin(const float* __restrict__ psum,
                                                const float* __restrict__ psq,
                                                float* __restrict__ st)
{
    const int ch = blockIdx.x;
    const int lane = threadIdx.x;
    float s = 0.f, q = 0.f;
    for (int i = lane; i < 392; i += 64) {
        s += psum[(size_t)ch * 392 + i];
        q += psq [(size_t)ch * 392 + i];
    }
#pragma unroll
    for (int off = 32; off; off >>= 1) { s += __shfl_xor(s, off); q += __shfl_xor(q, off); }
    if (lane == 0) {
        const float mean = s / 12544.f;
        const float var = q / 12544.f - mean * mean;
        st[ch] = mean;
        st[256 + ch] = rsqrtf(var + 1e-5f);
    }
}

// ---------------- attention: 32x32 MFMA, in-register P, KVBLK=64 --------
// grid (25, B=4, S=4), block 256 = 4 waves; wave owns 32 q-rows.
__global__ __launch_bounds__(256, 2) void attn_k(const short* __restrict__ Tt,
                                                 const short* __restrict__ Gpre,
                                                 const float* __restrict__ st,
                                                 short* __restrict__ Opart,
                                                 float* __restrict__ dpart)
{
    constexpr int N = NTOK;
    const int b = blockIdx.y, s = blockIdx.z;
    const int w = __builtin_amdgcn_readfirstlane(threadIdx.x >> 6);
    const int lane = threadIdx.x & 63;
    const int l31 = lane & 31, hi = lane >> 5;
    const int q0w = blockIdx.x * 128 + w * 32;

    __shared__ __align__(16) short Kl[2][64][128];  // 32 KB: K tile [m][ic]
    __shared__ __align__(16) short Vl[2][128][64];  // 32 KB: V tile [ic][m]

    const short* tb = Tt + (size_t)b * N * 128;
    const short* gb = Gpre + (size_t)b * 128 * N;

    // Q B-frags (col=q=l31, k(ic)=ks*16+hi*8+j), fold: q=(t-mu)*rho^2*log2e/N
    const float kexp = 1.44269504089f / (float)N;
    bf16x8 qf[8];
    {
        int row = q0w + l31; row = row < N ? row : N - 1;
        const short* qp = tb + (size_t)row * 128;
#pragma unroll
        for (int ks = 0; ks < 8; ks++) {
            const int c0 = ks * 16 + hi * 8;
            const bf16x8 v = *(const bf16x8*)(qp + c0);
            const f32x4 mA = *(const f32x4*)(st + c0);
            const f32x4 mB = *(const f32x4*)(st + c0 + 4);
            const f32x4 rA = *(const f32x4*)(st + 256 + c0);
            const f32x4 rB = *(const f32x4*)(st + 256 + c0 + 4);
            bf16x8 q;
#pragma unroll
            for (int j = 0; j < 4; j++) q[j] = f2bf((bf2f(v[j]) - mA[j]) * (rA[j] * rA[j] * kexp));
#pragma unroll
            for (int j = 0; j < 4; j++) q[4 + j] = f2bf((bf2f(v[4 + j]) - mB[j]) * (rB[j] * rB[j] * kexp));
            qf[ks] = q;
        }
    }

    f32x16 accv[4];
#pragma unroll
    for (int it = 0; it < 4; it++)
#pragma unroll
        for (int r = 0; r < 16; r++) accv[it][r] = 0.f;
    float denom = 0.f;

    auto STAGE = [&](int bufi, int m0) {
#pragma unroll
        for (int i = 0; i < 4; i++) {
            const int rb = w * 16 + i * 4;
            const int krow = rb + (lane >> 4);
            const int ls = (lane & 15) ^ (krow & 7);      // pre-swizzled source unit
            glds16(tb + (size_t)(m0 + krow) * 128 + ls * 8, (void*)&Kl[bufi][rb][0]);
        }
#pragma unroll
        for (int i = 0; i < 4; i++) {
            const int rb = w * 32 + i * 8;
            const int vrow = rb + (lane >> 3);
            const int ls = (lane & 7) ^ (vrow & 7);
            glds16(gb + (size_t)vrow * N + m0 + ls * 8, (void*)&Vl[bufi][rb][0]);
        }
    };

    const int nt = (49 - s + NSPLIT - 1) / NSPLIT;
    int mt = s;
    STAGE(0, mt * 64);
    __syncthreads();
    int buf = 0;

    const int fr = (l31 & 7) << 4;

    // exp2 + pack one 32-m half -> two PV A-frags (m 16-blocks)
    auto mkpa = [&](const f32x16 &sv, bf16x8 *dst) {
        float e[16];
#pragma unroll
        for (int r = 0; r < 16; r++) { e[r] = exp2f(sv[r]); denom += e[r]; }
        unsigned c0 = pk2(e[0], e[1]),  c1 = pk2(e[2], e[3]);
        unsigned c2 = pk2(e[4], e[5]),  c3 = pk2(e[6], e[7]);
        unsigned c4 = pk2(e[8], e[9]),  c5 = pk2(e[10], e[11]);
        unsigned c6 = pk2(e[12], e[13]), c7 = pk2(e[14], e[15]);
        pl32swap(c0, c2); pl32swap(c1, c3); pl32swap(c4, c6); pl32swap(c5, c7);
        union U { unsigned u[4]; bf16x8 v; } f0, f1;
        f0.u[0] = c0; f0.u[1] = c1; f0.u[2] = c2; f0.u[3] = c3;
        f1.u[0] = c4; f1.u[1] = c5; f1.u[2] = c6; f1.u[3] = c7;
        dst[0] = f0.v; dst[1] = f1.v;
    };

    for (int t = 0; t < nt; ++t) {
        if (t + 1 < nt) STAGE(buf ^ 1, (mt + NSPLIT) * 64);

        // --- QK^T: A = K rows (m), B = Q; dual independent chains ---
        f32x16 sv0, sv1;
#pragma unroll
        for (int r = 0; r < 16; r++) { sv0[r] = 0.f; sv1[r] = 0.f; }
#pragma unroll
        for (int ks = 0; ks < 8; ks++) {
            const int co = (ks * 32 + hi * 16) ^ fr;
            bf16x8 kf0 = *(const bf16x8*)((const char*)&Kl[buf][l31][0] + co);
            bf16x8 kf1 = *(const bf16x8*)((const char*)&Kl[buf][32 + l31][0] + co);
            sv0 = __builtin_amdgcn_mfma_f32_32x32x16_bf16(kf0, qf[ks], sv0, 0, 0, 0);
            sv1 = __builtin_amdgcn_mfma_f32_32x32x16_bf16(kf1, qf[ks], sv1, 0, 0, 0);
        }

        // --- exp2 -> in-register P A-frags (no LDS) ---
        bf16x8 pa[4];
        mkpa(sv0, &pa[0]);   // m 0..31  -> k-steps 0,1
        mkpa(sv1, &pa[2]);   // m 32..63 -> k-steps 2,3

        // --- PV: A = P (rows q), B = V (cols ic), k = m (4 k-steps) ---
#pragma unroll
        for (int kp = 0; kp < 4; kp++) {
            const int cv = kp * 32 + hi * 16;
#pragma unroll
            for (int it = 0; it < 4; it++) {
                const int row = it * 32 + l31;
                bf16x8 vf = *(const bf16x8*)((const char*)&Vl[buf][row][0] + (cv ^ fr));
                accv[it] = __builtin_amdgcn_mfma_f32_32x32x16_bf16(pa[kp], vf, accv[it], 0, 0, 0);
            }
        }
        __syncthreads();
        buf ^= 1;
        mt += NSPLIT;
    }

    // denom: lane holds sum over its m-half for q=l31; combine halves
    denom += __shfl_xor(denom, 32);

    short* op = Opart + ((size_t)(s * 4 + b)) * N * 128;
    // accv layout: col(l31)=ic_local, row=(r&3)+8(r>>2)+4hi = q_local
#pragma unroll
    for (int it = 0; it < 4; it++)
#pragma unroll
        for (int r = 0; r < 16; r++) {
            const int n = q0w + (r & 3) + 8 * (r >> 2) + 4 * hi;
            if (n < N) op[(size_t)n * 128 + it * 32 + l31] = f2bf(accv[it][r]);
        }
    if (lane < 32) {
        const int n = q0w + l31;
        if (n < N) dpart[(size_t)(s * 4 + b) * N + n] = denom;
    }
}

// ---------------- fused combine + de-norm + up conv + residual ----------
// grid (98, 4), block 256 = 4 waves.
__global__ __launch_bounds__(256) void conv_out_f(const short* __restrict__ Opart,
                                                  const float* __restrict__ dpart,
                                                  const float* __restrict__ st,
                                                  const short* __restrict__ wupb,
                                                  const float* __restrict__ bup,
                                                  const float* __restrict__ maps,
                                                  float* __restrict__ out)
{
    const int n0 = blockIdx.x * 32, b = blockIdx.y;
    const int t = threadIdx.x;

    __shared__ float denl[32];
    __shared__ __align__(16) short Yl[32][128];    // XOR-swizzled rows

    if (t < 32) {
        float d = 0.f;
#pragma unroll
        for (int s = 0; s < NSPLIT; s++) d += dpart[(size_t)(s * 4 + b) * NTOK + n0 + t];
        denl[t] = 1.0f / d;
    }
    __syncthreads();

#pragma unroll
    for (int g = 0; g < 2; g++) {
        const int e = t + g * 256;          // 0..511
        const int nl = e >> 4, icg = (e & 15) * 8;
        const float rdn = denl[nl];
        float sum[8] = {0.f, 0.f, 0.f, 0.f, 0.f, 0.f, 0.f, 0.f};
#pragma unroll
        for (int s = 0; s < NSPLIT; s++) {
            const size_t base = ((size_t)(s * 4 + b) * NTOK + n0 + nl) * 128 + icg;
            const bf16x8 a = *(const bf16x8*)(Opart + base);
#pragma unroll
            for (int j = 0; j < 8; j++) sum[j] += bf2f(a[j]);
        }
        const f32x4 mA = *(const f32x4*)(st + 128 + icg);
        const f32x4 mB = *(const f32x4*)(st + 128 + icg + 4);
        const f32x4 rA = *(const f32x4*)(st + 384 + icg);
        const f32x4 rB = *(const f32x4*)(st + 384 + icg + 4);
        s16x4 v0, v1;
#pragma unroll
        for (int j = 0; j < 4; j++) v0[j] = f2bf((sum[j] * rdn - mA[j]) * rA[j]);
#pragma unroll
        for (int j = 0; j < 4; j++) v1[j] = f2bf((sum[4 + j] * rdn - mB[j]) * rB[j]);
        char* ybase = (char*)&Yl[nl][0];
        const int sw = (nl & 7) << 4;
        *(s16x4*)(ybase + ((icg * 2) ^ sw)) = v0;
        *(s16x4*)(ybase + (((icg * 2) ^ sw) + 8)) = v1;
    }
    __syncthreads();

    const int wv = __builtin_amdgcn_readfirstlane(t >> 6);
    const int lane = t & 63;
    const int l15 = lane & 15, lhi = lane >> 4;
    const int c0 = wv * 128;
    const int fY = (l15 & 7) << 4;

    f32x4 acc[8][2];
#pragma unroll
    for (int g = 0; g < 8; g++)
#pragma unroll
        for (int j = 0; j < 2; j++) acc[g][j] = f32x4{0.f, 0.f, 0.f, 0.f};

#pragma unroll
    for (int ks = 0; ks < 4; ks++) {
        bf16x8 af[8], bv[2];
#pragma unroll
        for (int g = 0; g < 8; g++)
            af[g] = *(const bf16x8*)(wupb + (size_t)(c0 + g * 16 + l15) * 128 + ks * 32 + lhi * 8);
#pragma unroll
        for (int j = 0; j < 2; j++)
            bv[j] = *(const bf16x8*)((const char*)&Yl[j * 16 + l15][0] + ((ks * 64 + lhi * 16) ^ fY));
#pragma unroll
        for (int g = 0; g < 8; g++)
#pragma unroll
            for (int j = 0; j < 2; j++)
                acc[g][j] = __builtin_amdgcn_mfma_f32_16x16x32_bf16(af[g], bv[j], acc[g][j], 0, 0, 0);
    }
#pragma unroll
    for (int g = 0; g < 8; g++)
#pragma unroll
        for (int j = 0; j < 2; j++)
#pragma unroll
            for (int r = 0; r < 4; r++) {
                const int c = c0 + g * 16 + lhi * 4 + r;
                const int n = n0 + j * 16 + l15;
                const size_t o = ((size_t)b * 512 + c) * NTOK + n;
                out[o] = acc[g][j][r] + bup[c] + maps[o];
            }
}

extern "C" void kernel_launch(void* const* d_in, const int* in_sizes, int n_in,
                              void* d_out, int out_size, void* d_ws, size_t ws_size,
                              hipStream_t stream)
{
    const float* maps    = (const float*)d_in[0];
    const float* w_theta = (const float*)d_in[1];
    const float* w_glob  = (const float*)d_in[5];
    const float* w_up    = (const float*)d_in[7];
    const float* b_up    = (const float*)d_in[8];
    float* out = (float*)d_out;

    // workspace (~21 MB)
    short* Tt    = (short*)d_ws;               // NELEM (theta pre-norm, [b][n][ic])
    short* Gpre  = Tt + NELEM;                 // NELEM (glob pre-norm, [b][ic][n])
    short* Wb    = Gpre + NELEM;               // 131072 shorts
    short* wupb  = Wb + 131072;                // 65536 shorts
    float* st    = (float*)(wupb + 65536);     // 512 f32
    float* psum  = st + 512;                   // 256*392 f32
    float* psq   = psum + 100352;              // 256*392 f32
    float* dpart = psq + 100352;               // NSPLIT*4*3136 f32
    short* Opart = (short*)(dpart + 50176);    // NSPLIT*4*3136*128 bf16 = 12.8 MB

    prep_w    <<<768,             256, 0, stream>>>(w_theta, w_glob, w_up, Wb, wupb);
    conv_in_f <<<dim3(98, 4),     256, 0, stream>>>(maps, Wb, Tt, Gpre, psum, psq);
    stats_fin <<<256,             64,  0, stream>>>(psum, psq, st);
    attn_k    <<<dim3(25, 4, NSPLIT), 256, 0, stream>>>(Tt, Gpre, st, Opart, dpart);
    conv_out_f<<<dim3(98, 4),     256, 0, stream>>>(Opart, dpart, st, wupb, b_up, maps, out);
}